// Round 2
// baseline (11717.820 us; speedup 1.0000x reference)
//
#include <hip/hip_runtime.h>
#include <math.h>

// ---------------- problem constants (fixed by setup_inputs) ----------------
#define NB 16          // beams
#define NR 100         // rois
#define NV 50000       // vocab (Vv)
#define ND 1024        // rnn size
#define NT 20          // seq length
#define VP1 50001      // NV+1 (word head width)
#define VTT 50101      // VP1 + NR (merged vocab)
#define RP1 101        // NR+1
#define NEGF (-1e10f)

struct P {
  const float* embed; const float* Wx; const float* Wh; const float* Wc;
  const float* Wl; const float* Wd; const float* rnn0; const float* det0;
  const float* h0; const float* pool; const float* ppls; const float* pnt;
  float* logits;   // [16][50001]
  float* lse;      // [16]
  float* dlp;      // [16][101] det log-softmax
  float* rnnT;     // [1024][16] transposed rnn_out (K1 input)
  float* hst;      // [16][1024] h state
  float* hhgT;     // [1024][16] gathered hh, transposed
  float* xtT;      // [1024][16]
  float* ctxT;     // [1024][16]
  float* mask0; float* mask1;       // [16][101] ping-pong
  int* bs0; int* bs1;               // [20][16] ping-pong
  float* blp0; float* blp1;         // [20][16] ping-pong
  float* lpsum;    // [16]
  float* pkv; unsigned* pkf;        // [32*16] per-block top16
  float* part;     // [32][16][1024] gemm partials
};

__device__ __forceinline__ bool better(float av, unsigned af, float bv, unsigned bf){
  return (av > bv) || (av == bv && af < bf);
}

// ---------------- K0: init (transpose rnn0, zero beam state) ----------------
__global__ __launch_bounds__(256) void k0_init(P p){
  int i = blockIdx.x*256 + threadIdx.x;
  int n = gridDim.x*256;
  for (int o=i; o<NB*ND; o+=n){ int b=o>>10, k=o&1023; p.rnnT[k*NB+b] = p.rnn0[o]; }
  for (int o=i; o<NT*NB; o+=n){ p.bs0[o]=0; p.bs1[o]=0; p.blp0[o]=0.f; p.blp1[o]=0.f; }
  for (int o=i; o<NB; o+=n) p.lpsum[o]=0.f;
}

// ---------------- K1: logits = rnn_out @ Wl  [16][50001] ----------------
// 782 blocks x 256 thr: 64 j-cols/block, 4-way k split, LDS reduce.
__global__ __launch_bounds__(256) void k1_logits(const float* __restrict__ Wl,
                                                 const float* __restrict__ rnnT,
                                                 float* __restrict__ logits){
  __shared__ float red[256*16];
  int tid = threadIdx.x;
  int jt = tid & 63, ks = tid >> 6;
  int j = blockIdx.x*64 + jt;
  float acc[16];
  #pragma unroll
  for (int b=0;b<16;++b) acc[b]=0.f;
  if (j < VP1){
    int k0 = ks*256;
    #pragma unroll 2
    for (int k=k0;k<k0+256;++k){
      float wv = Wl[(size_t)k*VP1 + j];
      const float4* r4 = reinterpret_cast<const float4*>(rnnT) + (size_t)k*4;
      float4 a0=r4[0], a1=r4[1], a2=r4[2], a3=r4[3];
      acc[0]=fmaf(a0.x,wv,acc[0]);  acc[1]=fmaf(a0.y,wv,acc[1]);
      acc[2]=fmaf(a0.z,wv,acc[2]);  acc[3]=fmaf(a0.w,wv,acc[3]);
      acc[4]=fmaf(a1.x,wv,acc[4]);  acc[5]=fmaf(a1.y,wv,acc[5]);
      acc[6]=fmaf(a1.z,wv,acc[6]);  acc[7]=fmaf(a1.w,wv,acc[7]);
      acc[8]=fmaf(a2.x,wv,acc[8]);  acc[9]=fmaf(a2.y,wv,acc[9]);
      acc[10]=fmaf(a2.z,wv,acc[10]); acc[11]=fmaf(a2.w,wv,acc[11]);
      acc[12]=fmaf(a3.x,wv,acc[12]); acc[13]=fmaf(a3.y,wv,acc[13]);
      acc[14]=fmaf(a3.z,wv,acc[14]); acc[15]=fmaf(a3.w,wv,acc[15]);
    }
  }
  #pragma unroll
  for (int b=0;b<16;++b) red[tid*16+b] = acc[b];
  __syncthreads();
  #pragma unroll
  for (int u=0;u<4;++u){
    int o = tid*4+u; int jj = o>>4, b = o&15;
    float s = red[jj*16+b] + red[(64+jj)*16+b] + red[(128+jj)*16+b] + red[(192+jj)*16+b];
    int jg = blockIdx.x*64 + jj;
    if (jg < VP1) logits[(size_t)b*VP1 + jg] = s;
  }
}

// ---------------- K2: det head + det log-softmax + row lse ----------------
__global__ __launch_bounds__(256) void k2_lse_det(P p, int t){
  int b = blockIdx.x, tid = threadIdx.x;
  __shared__ float sm[256];
  __shared__ float dr[RP1];
  __shared__ float dms[2];
  if (tid < RP1){
    float v;
    if (t == 0) v = p.det0[b*RP1 + tid];
    else {
      v = 0.f;
      const float* hr = p.hst + b*ND;
      for (int k=0;k<ND;++k) v = fmaf(hr[k], p.Wd[k*RP1 + tid], v);
    }
    dr[tid] = v;
  }
  __syncthreads();
  if (tid == 0){
    float m = dr[0];
    for (int u=1;u<RP1;++u) m = fmaxf(m, dr[u]);
    float s = 0.f;
    for (int u=0;u<RP1;++u) s += expf(dr[u]-m);
    dms[0]=m; dms[1]=logf(s);
  }
  __syncthreads();
  if (tid < RP1) p.dlp[b*RP1 + tid] = dr[tid] - dms[0] - dms[1];
  // lse over the 50001 logits of row b
  const float* lr = p.logits + (size_t)b*VP1;
  float mx = -INFINITY;
  for (int j=tid;j<VP1;j+=256) mx = fmaxf(mx, lr[j]);
  sm[tid]=mx; __syncthreads();
  for (int s=128;s;s>>=1){ if(tid<s) sm[tid]=fmaxf(sm[tid],sm[tid+s]); __syncthreads(); }
  float rm = sm[0]; __syncthreads();
  float su = 0.f;
  for (int j=tid;j<VP1;j+=256) su += expf(lr[j]-rm);
  sm[tid]=su; __syncthreads();
  for (int s=128;s;s>>=1){ if(tid<s) sm[tid]+=sm[tid+s]; __syncthreads(); }
  if (tid==0) p.lse[b] = rm + logf(sm[0]);
}

// ---------------- K3: candidates + per-block top16 (32 blocks) ----------------
__global__ __launch_bounds__(256) void k3_cand(P p, int t){
  int tid = threadIdx.x;
  int gid = blockIdx.x*256 + tid;
  float lv[16]; unsigned lf[16];
  #pragma unroll
  for (int u=0;u<16;++u){ lv[u]=-3e38f; lf[u]=0xFFFFFFFFu; }
  float wmin = -3e38f; unsigned wfmin = 0xFFFFFFFFu;
  for (int o=gid; o<NB*VTT; o+=32*256){
    int b = o / VTT;
    int j = o - b*VTT;
    float v;
    if (j < VP1) v = p.lpsum[b] + p.logits[(size_t)b*VP1 + j] - p.lse[b] + p.dlp[b*RP1];
    else        v = p.lpsum[b] + p.dlp[b*RP1 + (j - NV)];
    if (t==0 && b>0) v = NEGF;
    unsigned f = (unsigned)o;
    if (!better(v,f,wmin,wfmin)) continue;
    // replace the worst entry (static-indexed ops only)
    int mp = 0; float mv2 = lv[0]; unsigned mf2 = lf[0];
    #pragma unroll
    for (int u=1;u<16;++u){ if (better(mv2,mf2,lv[u],lf[u])){ mp=u; mv2=lv[u]; mf2=lf[u]; } }
    #pragma unroll
    for (int u=0;u<16;++u){ if (u==mp){ lv[u]=v; lf[u]=f; } }
    wmin = lv[0]; wfmin = lf[0];
    #pragma unroll
    for (int u=1;u<16;++u){ if (better(wmin,wfmin,lv[u],lf[u])){ wmin=lv[u]; wfmin=lf[u]; } }
  }
  // block merge: 16 rounds of tree-argmax over 256 per-thread bests
  __shared__ float rv[256]; __shared__ unsigned rf[256];
  for (int r=0;r<16;++r){
    float bv = lv[0]; unsigned bf = lf[0];
    #pragma unroll
    for (int u=1;u<16;++u){ if (better(lv[u],lf[u],bv,bf)){ bv=lv[u]; bf=lf[u]; } }
    rv[tid]=bv; rf[tid]=bf; __syncthreads();
    for (int s=128;s;s>>=1){
      if (tid<s && better(rv[tid+s],rf[tid+s],rv[tid],rf[tid])){ rv[tid]=rv[tid+s]; rf[tid]=rf[tid+s]; }
      __syncthreads();
    }
    float wv = rv[0]; unsigned wf = rf[0];
    if (tid==0){ p.pkv[blockIdx.x*16+r]=wv; p.pkf[blockIdx.x*16+r]=wf; }
    __syncthreads();
    #pragma unroll
    for (int u=0;u<16;++u){ if (lf[u]==wf && lv[u]==wv){ lv[u]=-3e38f; lf[u]=0xFFFFFFFFu; } }
    __syncthreads();
  }
}

// ---------------- K4: final merge + beam update + attention (16 blocks) ------
__global__ __launch_bounds__(256) void k4_beam(P p, int t){
  int bi = blockIdx.x, tid = threadIdx.x;
  __shared__ float mv[512]; __shared__ unsigned mu[512];
  __shared__ float rv[256]; __shared__ unsigned rf[256];
  __shared__ float hhs[ND];
  __shared__ float msk[RP1];
  __shared__ float att[NR];
  __shared__ int s_q, s_c, s_it; __shared__ float s_local;

  mv[tid]=p.pkv[tid]; mu[tid]=p.pkf[tid];
  mv[tid+256]=p.pkv[tid+256]; mu[tid+256]=p.pkf[tid+256];
  __syncthreads();
  float wv=0.f; unsigned wf=0u;
  for (int r=0;r<=bi;++r){
    float bv = mv[tid]; unsigned bf = mu[tid];
    if (better(mv[tid+256],mu[tid+256],bv,bf)){ bv=mv[tid+256]; bf=mu[tid+256]; }
    rv[tid]=bv; rf[tid]=bf; __syncthreads();
    for (int s=128;s;s>>=1){
      if (tid<s && better(rv[tid+s],rf[tid+s],rv[tid],rf[tid])){ rv[tid]=rv[tid+s]; rf[tid]=rf[tid+s]; }
      __syncthreads();
    }
    wv=rv[0]; wf=rf[0]; __syncthreads();
    if (r<bi){
      if (mu[tid]==wf && mv[tid]==wv){ mv[tid]=-3e38f; mu[tid]=0xFFFFFFFFu; }
      if (mu[tid+256]==wf && mv[tid+256]==wv){ mv[tid+256]=-3e38f; mu[tid+256]=0xFFFFFFFFu; }
      __syncthreads();
    }
  }
  if (tid==0){
    int q = (int)(wf / VTT); int c = (int)(wf - (unsigned)q*VTT);
    int it;
    if (c > NV){
      int ridx = c - VP1;
      int vis = (int)p.ppls[((size_t)bi*NR + ridx)*6 + 4];
      it = vis + NV;
    } else it = c;
    float local = (c < VP1) ? (p.logits[(size_t)q*VP1 + c] - p.lse[q] + p.dlp[q*RP1])
                            : p.dlp[q*RP1 + (c - NV)];
    s_q=q; s_c=c; s_it=it; s_local=local;
    p.lpsum[bi] = (c==0) ? -1000.0f : wv;
  }
  __syncthreads();
  int q = s_q, c = s_c, it = s_it;
  // beam_seq / beam_lp reshuffle (ping-pong)
  const int* bss = (t&1)? p.bs1 : p.bs0;   int* bsd = (t&1)? p.bs0 : p.bs1;
  const float* lps = (t&1)? p.blp1: p.blp0; float* lpd = (t&1)? p.blp0: p.blp1;
  if (tid < t){ bsd[tid*NB+bi] = bss[tid*NB+q]; lpd[tid*NB+bi] = lps[tid*NB+q]; }
  if (tid == t){ bsd[t*NB+bi] = c; lpd[t*NB+bi] = s_local; }
  // mask gather + ROI scatter
  const float* ms = (t==0) ? p.pnt : ((t&1)? p.mask1 : p.mask0);
  float* md = (t&1)? p.mask0 : p.mask1;
  if (tid < RP1){
    float m = ms[q*RP1 + tid];
    if (tid == 0) m = 0.f;
    if (c > NV && tid == (c - VP1) + 1) m = 1.0f;
    msk[tid] = m; md[bi*RP1 + tid] = m;
  }
  // hh gather + xt embed
  const float* hprev = (t==0)? p.h0 : p.hst;
  for (int d=tid; d<ND; d+=256){
    float v = hprev[(size_t)q*ND + d];
    hhs[d] = v; p.hhgT[d*NB+bi] = v;
  }
  for (int d=tid; d<ND; d+=256) p.xtT[d*NB+bi] = p.embed[(size_t)it*ND + d];
  __syncthreads();
  // attention scores (4 r-groups x 64-lane dot)
  int lane = tid & 63, rg = tid >> 6;
  for (int r=rg; r<NR; r+=4){
    float s = 0.f;
    const float* pf = p.pool + ((size_t)bi*NR + r)*ND;
    for (int d=lane; d<ND; d+=64) s = fmaf(hhs[d], pf[d], s);
    #pragma unroll
    for (int off=32;off;off>>=1) s += __shfl_down(s, off);
    if (lane==0){
      s *= 0.03125f;                       // / sqrt(1024)
      att[r] = (msk[r+1] > 0.f) ? NEGF : s;
    }
  }
  __syncthreads();
  if (tid < 64){
    float a  = (tid    < NR) ? att[tid]    : -INFINITY;
    float a2 = (tid+64 < NR) ? att[tid+64] : -INFINITY;
    float m = fmaxf(a, a2);
    #pragma unroll
    for (int off=32;off;off>>=1) m = fmaxf(m, __shfl_down(m, off));
    m = __shfl(m, 0);
    float e1 = (tid    < NR) ? expf(a - m)  : 0.f;
    float e2 = (tid+64 < NR) ? expf(a2 - m) : 0.f;
    float s = e1 + e2;
    #pragma unroll
    for (int off=32;off;off>>=1) s += __shfl_down(s, off);
    s = __shfl(s, 0);
    if (tid    < NR) att[tid]    = e1 / s;
    if (tid+64 < NR) att[tid+64] = e2 / s;
  }
  __syncthreads();
  // ctx = att . pool
  for (int d=tid; d<ND; d+=256){
    float cx = 0.f;
    const float* pf = p.pool + (size_t)bi*NR*ND + d;
    #pragma unroll 4
    for (int r=0;r<NR;++r) cx = fmaf(att[r], pf[(size_t)r*ND], cx);
    p.ctxT[d*NB+bi] = cx;
  }
}

// ---------------- K5: fused 3-matrix RNN GEMM partials (128 blocks) ----------
__global__ __launch_bounds__(256) void k5_rnn(const float* __restrict__ Wx,
    const float* __restrict__ Wh, const float* __restrict__ Wc,
    const float* __restrict__ xtT, const float* __restrict__ hhgT,
    const float* __restrict__ ctxT, float* __restrict__ part){
  int tid = threadIdx.x;
  int jb = blockIdx.x & 3, ks = blockIdx.x >> 2;
  int j = jb*256 + tid;
  int k0 = ks*32;
  float acc[16];
  #pragma unroll
  for (int b=0;b<16;++b) acc[b]=0.f;
  for (int k=k0;k<k0+32;++k){
    float wx = Wx[(size_t)k*ND + j];
    float wh = Wh[(size_t)k*ND + j];
    float wc = Wc[(size_t)k*ND + j];
    const float4* xv = reinterpret_cast<const float4*>(xtT)  + (size_t)k*4;
    const float4* hv = reinterpret_cast<const float4*>(hhgT) + (size_t)k*4;
    const float4* cv = reinterpret_cast<const float4*>(ctxT) + (size_t)k*4;
    float4 x0=xv[0],x1=xv[1],x2=xv[2],x3=xv[3];
    float4 h0=hv[0],h1=hv[1],h2=hv[2],h3=hv[3];
    float4 c0=cv[0],c1=cv[1],c2=cv[2],c3=cv[3];
    acc[0]=fmaf(x0.x,wx,fmaf(h0.x,wh,fmaf(c0.x,wc,acc[0])));
    acc[1]=fmaf(x0.y,wx,fmaf(h0.y,wh,fmaf(c0.y,wc,acc[1])));
    acc[2]=fmaf(x0.z,wx,fmaf(h0.z,wh,fmaf(c0.z,wc,acc[2])));
    acc[3]=fmaf(x0.w,wx,fmaf(h0.w,wh,fmaf(c0.w,wc,acc[3])));
    acc[4]=fmaf(x1.x,wx,fmaf(h1.x,wh,fmaf(c1.x,wc,acc[4])));
    acc[5]=fmaf(x1.y,wx,fmaf(h1.y,wh,fmaf(c1.y,wc,acc[5])));
    acc[6]=fmaf(x1.z,wx,fmaf(h1.z,wh,fmaf(c1.z,wc,acc[6])));
    acc[7]=fmaf(x1.w,wx,fmaf(h1.w,wh,fmaf(c1.w,wc,acc[7])));
    acc[8]=fmaf(x2.x,wx,fmaf(h2.x,wh,fmaf(c2.x,wc,acc[8])));
    acc[9]=fmaf(x2.y,wx,fmaf(h2.y,wh,fmaf(c2.y,wc,acc[9])));
    acc[10]=fmaf(x2.z,wx,fmaf(h2.z,wh,fmaf(c2.z,wc,acc[10])));
    acc[11]=fmaf(x2.w,wx,fmaf(h2.w,wh,fmaf(c2.w,wc,acc[11])));
    acc[12]=fmaf(x3.x,wx,fmaf(h3.x,wh,fmaf(c3.x,wc,acc[12])));
    acc[13]=fmaf(x3.y,wx,fmaf(h3.y,wh,fmaf(c3.y,wc,acc[13])));
    acc[14]=fmaf(x3.z,wx,fmaf(h3.z,wh,fmaf(c3.z,wc,acc[14])));
    acc[15]=fmaf(x3.w,wx,fmaf(h3.w,wh,fmaf(c3.w,wc,acc[15])));
  }
  #pragma unroll
  for (int b=0;b<16;++b) part[((size_t)ks*16 + b)*ND + j] = acc[b];
}

// ---------------- K6: reduce partials + tanh -> h_new (64 blocks) ------------
__global__ __launch_bounds__(256) void k6_tanh(P p){
  int o = blockIdx.x*256 + threadIdx.x;   // 0..16383
  int b = o >> 10, j = o & 1023;
  float s = 0.f;
  for (int ks=0; ks<32; ++ks) s += p.part[((size_t)ks*16 + b)*ND + j];
  float hv = tanhf(s);
  p.hst[o] = hv;
  p.rnnT[j*NB + b] = hv;
}

// ---------------- K7: pack outputs as FLOAT32 (d_out is f32, not bf16) -------
__global__ __launch_bounds__(256) void k7_out(P p, float* out){
  int i = blockIdx.x*256 + threadIdx.x;
  if (i < NT*NB)            out[i] = (float)p.bs0[i];
  else if (i < 2*NT*NB)     out[i] = p.blp0[i - NT*NB];
  else if (i < 2*NT*NB+NB)  out[i] = p.lpsum[i - 2*NT*NB];
}

// ---------------- host ----------------
extern "C" void kernel_launch(void* const* d_in, const int* in_sizes, int n_in,
                              void* d_out, int out_size, void* d_ws, size_t ws_size,
                              hipStream_t stream) {
  P p;
  p.embed = (const float*)d_in[0];
  p.Wx    = (const float*)d_in[1];
  p.Wh    = (const float*)d_in[2];
  p.Wc    = (const float*)d_in[3];
  p.Wl    = (const float*)d_in[4];
  p.Wd    = (const float*)d_in[5];
  p.rnn0  = (const float*)d_in[6];
  p.det0  = (const float*)d_in[7];
  p.h0    = (const float*)d_in[8];
  p.pool  = (const float*)d_in[9];
  p.ppls  = (const float*)d_in[10];
  p.pnt   = (const float*)d_in[11];

  char* ws = (char*)d_ws;
  size_t off = 0;
  auto A = [&](size_t nfloats)->void* {
    void* r = ws + off;
    off += ((nfloats*4) + 255) & ~(size_t)255;
    return r;
  };
  p.logits = (float*)A((size_t)NB*VP1);
  p.lse    = (float*)A(NB);
  p.dlp    = (float*)A(NB*RP1);
  p.rnnT   = (float*)A(ND*NB);
  p.hst    = (float*)A(NB*ND);
  p.hhgT   = (float*)A(ND*NB);
  p.xtT    = (float*)A(ND*NB);
  p.ctxT   = (float*)A(ND*NB);
  p.mask0  = (float*)A(NB*RP1);
  p.mask1  = (float*)A(NB*RP1);
  p.bs0    = (int*)A(NT*NB);
  p.bs1    = (int*)A(NT*NB);
  p.blp0   = (float*)A(NT*NB);
  p.blp1   = (float*)A(NT*NB);
  p.lpsum  = (float*)A(NB);
  p.pkv    = (float*)A(512);
  p.pkf    = (unsigned*)A(512);
  p.part   = (float*)A((size_t)32*NB*ND);
  if (off > ws_size) return;   // workspace too small; fail cleanly

  k0_init<<<64,256,0,stream>>>(p);
  for (int t=0; t<NT; ++t){
    k1_logits<<<(VP1+63)/64,256,0,stream>>>(p.Wl, p.rnnT, p.logits);
    k2_lse_det<<<NB,256,0,stream>>>(p, t);
    k3_cand<<<32,256,0,stream>>>(p, t);
    k4_beam<<<NB,256,0,stream>>>(p, t);
    k5_rnn<<<128,256,0,stream>>>(p.Wx, p.Wh, p.Wc, p.xtT, p.hhgT, p.ctxT, p.part);
    k6_tanh<<<64,256,0,stream>>>(p);
  }
  k7_out<<<3,256,0,stream>>>(p, (float*)d_out);
}

// Round 3
// 6416.486 us; speedup vs baseline: 1.8262x; 1.8262x over previous
//
#include <hip/hip_runtime.h>
#include <math.h>

#define NB 16
#define NR 100
#define NV 50000
#define ND 1024
#define NT 20
#define VP1 50001
#define VTT 50101
#define RP1 101
#define NEGF (-1e10f)
#define LSE_TILES 49   // ceil(50001/1024)

struct P {
  const float* embed; const float* Wx; const float* Wh; const float* Wc;
  const float* Wl; const float* Wd; const float* rnn0; const float* det0;
  const float* h0; const float* pool; const float* ppls; const float* pnt;
  float* logits;   // [16][50001]
  float* lse;      // [16]
  float* dlp;      // [16][101]
  float* rnnT;     // [1024][16]
  float* hst;      // [16][1024]
  float* hhgT;     // [1024][16]
  float* xtT;      // [1024][16]
  float* ctxT;     // [1024][16]
  float* mask0; float* mask1;       // [16][101] ping-pong
  int* bs0; int* bs1;               // [20][16] ping-pong
  float* blp0; float* blp1;         // [20][16] ping-pong
  float* lpsum;    // [16]
  float* pkv; unsigned* pkf;        // [32*16]
  float* part;     // [32][16][1024]
  float* blkM; float* blkS;         // [16*49] lse partials
  int* qsel; int* itsel;            // [16]
};

__device__ __forceinline__ bool better(float av, unsigned af, float bv, unsigned bf){
  return (av > bv) || (av == bv && af < bf);
}
__device__ __forceinline__ void lsecomb(float& m, float& s, float m2, float s2){
  float M = fmaxf(m, m2);
  if (M == -INFINITY){ m = M; s = 0.f; return; }
  s = s*expf(m - M) + s2*expf(m2 - M);
  m = M;
}

// ---------------- K0: init ----------------
__global__ __launch_bounds__(256) void k0_init(P p){
  int i = blockIdx.x*256 + threadIdx.x;
  int n = gridDim.x*256;
  for (int o=i; o<NB*ND; o+=n){ int b=o>>10, k=o&1023; p.rnnT[k*NB+b] = p.rnn0[o]; }
  for (int o=i; o<NT*NB; o+=n){ p.bs0[o]=0; p.bs1[o]=0; p.blp0[o]=0.f; p.blp1[o]=0.f; }
  for (int o=i; o<NB; o+=n) p.lpsum[o]=0.f;
}

// ---------------- K1: logits = rnn_out @ Wl ----------------
// 391 blocks x 256 thr: 128 j/block (2 per thread), 4-way k split.
__global__ __launch_bounds__(256) void k1_logits(const float* __restrict__ Wl,
    const float* __restrict__ rnnT, float* __restrict__ logits){
  __shared__ float red[4][128][17];
  int tid = threadIdx.x;
  int jt = tid & 63, ks = tid >> 6;
  int B0 = blockIdx.x * 128;
  int j0 = B0 + jt, j1 = j0 + 64;
  const float* p0 = Wl + (j0 < VP1 ? j0 : VP1-1);
  const float* p1 = Wl + (j1 < VP1 ? j1 : VP1-1);
  float a0[16], a1[16];
  #pragma unroll
  for (int b=0;b<16;++b){ a0[b]=0.f; a1[b]=0.f; }
  const float4* rT = reinterpret_cast<const float4*>(rnnT);
  size_t koff = (size_t)(ks*256) * VP1;
  for (int k=ks*256; k<ks*256+256; ++k, koff += VP1){
    float w0 = p0[koff], w1 = p1[koff];
    float4 r0 = rT[k*4+0], r1 = rT[k*4+1], r2 = rT[k*4+2], r3 = rT[k*4+3];
    a0[0]=fmaf(r0.x,w0,a0[0]);  a1[0]=fmaf(r0.x,w1,a1[0]);
    a0[1]=fmaf(r0.y,w0,a0[1]);  a1[1]=fmaf(r0.y,w1,a1[1]);
    a0[2]=fmaf(r0.z,w0,a0[2]);  a1[2]=fmaf(r0.z,w1,a1[2]);
    a0[3]=fmaf(r0.w,w0,a0[3]);  a1[3]=fmaf(r0.w,w1,a1[3]);
    a0[4]=fmaf(r1.x,w0,a0[4]);  a1[4]=fmaf(r1.x,w1,a1[4]);
    a0[5]=fmaf(r1.y,w0,a0[5]);  a1[5]=fmaf(r1.y,w1,a1[5]);
    a0[6]=fmaf(r1.z,w0,a0[6]);  a1[6]=fmaf(r1.z,w1,a1[6]);
    a0[7]=fmaf(r1.w,w0,a0[7]);  a1[7]=fmaf(r1.w,w1,a1[7]);
    a0[8]=fmaf(r2.x,w0,a0[8]);  a1[8]=fmaf(r2.x,w1,a1[8]);
    a0[9]=fmaf(r2.y,w0,a0[9]);  a1[9]=fmaf(r2.y,w1,a1[9]);
    a0[10]=fmaf(r2.z,w0,a0[10]); a1[10]=fmaf(r2.z,w1,a1[10]);
    a0[11]=fmaf(r2.w,w0,a0[11]); a1[11]=fmaf(r2.w,w1,a1[11]);
    a0[12]=fmaf(r3.x,w0,a0[12]); a1[12]=fmaf(r3.x,w1,a1[12]);
    a0[13]=fmaf(r3.y,w0,a0[13]); a1[13]=fmaf(r3.y,w1,a1[13]);
    a0[14]=fmaf(r3.z,w0,a0[14]); a1[14]=fmaf(r3.z,w1,a1[14]);
    a0[15]=fmaf(r3.w,w0,a0[15]); a1[15]=fmaf(r3.w,w1,a1[15]);
  }
  #pragma unroll
  for (int b=0;b<16;++b){ red[ks][jt][b] = a0[b]; red[ks][jt+64][b] = a1[b]; }
  __syncthreads();
  int jl = tid & 127, bh = tid >> 7;
  int j = B0 + jl;
  #pragma unroll
  for (int i=0;i<8;++i){
    int b = i*2 + bh;
    float v = red[0][jl][b] + red[1][jl][b] + red[2][jl][b] + red[3][jl][b];
    if (j < VP1) logits[(size_t)b*VP1 + j] = v;
  }
}

// ---------------- K2a: per-tile LSE partials (49 x 16 blocks) ----------------
__global__ __launch_bounds__(256) void k2a_lsepart(const float* __restrict__ logits,
    float* __restrict__ blkM, float* __restrict__ blkS){
  int tile = blockIdx.x, b = blockIdx.y;
  int tid = threadIdx.x;
  const float* lr = logits + (size_t)b*VP1 + tile*1024;
  int lim = VP1 - tile*1024;
  float m = -INFINITY, s = 0.f;
  #pragma unroll
  for (int c=0;c<4;++c){
    int j = c*256 + tid;
    if (j < lim){
      float x = lr[j];
      if (x > m){ s = s*expf(m-x) + 1.f; m = x; }
      else s += expf(x-m);
    }
  }
  #pragma unroll
  for (int off=32; off; off>>=1){
    float m2 = __shfl_down(m, off), s2 = __shfl_down(s, off);
    lsecomb(m, s, m2, s2);
  }
  __shared__ float wm[4], ws[4];
  int w = tid >> 6;
  if ((tid & 63) == 0){ wm[w] = m; ws[w] = s; }
  __syncthreads();
  if (tid == 0){
    float M = wm[0], S = ws[0];
    lsecomb(M, S, wm[1], ws[1]);
    lsecomb(M, S, wm[2], ws[2]);
    lsecomb(M, S, wm[3], ws[3]);
    blkM[b*LSE_TILES + tile] = M; blkS[b*LSE_TILES + tile] = S;
  }
}

// ---------------- K2b: lse combine (blocks 0-15) + det head (blocks 16-31) ---
__global__ __launch_bounds__(512) void k2b_lse_det(P p, int t){
  int bx = blockIdx.x, tid = threadIdx.x;
  if (bx < 16){
    if (tid < 64){
      int b = bx;
      float m = -INFINITY, s = 0.f;
      if (tid < LSE_TILES){ m = p.blkM[b*LSE_TILES + tid]; s = p.blkS[b*LSE_TILES + tid]; }
      #pragma unroll
      for (int off=32; off; off>>=1){
        float m2 = __shfl_down(m, off), s2 = __shfl_down(s, off);
        lsecomb(m, s, m2, s2);
      }
      if (tid == 0) p.lse[b] = m + logf(s);
    }
    return;
  }
  int b = bx - 16;
  __shared__ float dred[4][129];
  __shared__ float ddet[128];
  int jj = tid & 127, ks = tid >> 7;
  if (t == 0){
    if (tid < 128) ddet[tid] = (tid < RP1) ? p.det0[b*RP1 + tid] : -INFINITY;
    __syncthreads();
  } else {
    float a = 0.f;
    if (jj < RP1){
      const float* hr = p.hst + b*ND;
      for (int k=ks*256; k<ks*256+256; ++k)
        a = fmaf(hr[k], p.Wd[(size_t)k*RP1 + jj], a);
    }
    dred[ks][jj] = a;
    __syncthreads();
    if (tid < 128)
      ddet[tid] = (tid < RP1) ? (dred[0][tid]+dred[1][tid]+dred[2][tid]+dred[3][tid]) : -INFINITY;
    __syncthreads();
  }
  if (tid < 64){
    float a = ddet[tid], a2 = ddet[tid+64];
    float m = fmaxf(a, a2);
    #pragma unroll
    for (int off=32; off; off>>=1) m = fmaxf(m, __shfl_down(m, off));
    m = __shfl(m, 0);
    float e1 = (tid < RP1) ? expf(a - m) : 0.f;
    float e2 = (tid+64 < RP1) ? expf(a2 - m) : 0.f;
    float s = e1 + e2;
    #pragma unroll
    for (int off=32; off; off>>=1) s += __shfl_down(s, off);
    s = __shfl(s, 0);
    float ls = logf(s);
    if (tid < RP1)     p.dlp[b*RP1 + tid]      = a  - m - ls;
    if (tid+64 < RP1)  p.dlp[b*RP1 + tid + 64] = a2 - m - ls;
  }
}

// ---------------- K3: candidates + per-block top16 (32 blocks) ----------------
__global__ __launch_bounds__(256) void k3_cand(P p, int t){
  int tid = threadIdx.x;
  int gid = blockIdx.x*256 + tid;
  float lv[16]; unsigned lf[16];
  #pragma unroll
  for (int u=0;u<16;++u){ lv[u]=-3e38f; lf[u]=0xFFFFFFFFu; }
  float wmin = -3e38f; unsigned wfmin = 0xFFFFFFFFu;
  for (int b=0;b<16;++b){
    if (t==0 && b>0) break;
    float cA = p.lpsum[b] - p.lse[b] + p.dlp[b*RP1];
    float cB = p.lpsum[b];
    const float* lrow = p.logits + (size_t)b*VP1;
    unsigned fbase = (unsigned)(b*VTT);
    for (int j=gid; j<VTT; j+=8192){
      float v = (j < VP1) ? (cA + lrow[j]) : (cB + p.dlp[b*RP1 + (j - NV)]);
      unsigned f = fbase + (unsigned)j;
      if (!better(v,f,wmin,wfmin)) continue;
      int mp = 0; float mv2 = lv[0]; unsigned mf2 = lf[0];
      #pragma unroll
      for (int u=1;u<16;++u){ if (better(mv2,mf2,lv[u],lf[u])){ mp=u; mv2=lv[u]; mf2=lf[u]; } }
      #pragma unroll
      for (int u=0;u<16;++u){ if (u==mp){ lv[u]=v; lf[u]=f; } }
      wmin = lv[0]; wfmin = lf[0];
      #pragma unroll
      for (int u=1;u<16;++u){ if (better(wmin,wfmin,lv[u],lf[u])){ wmin=lv[u]; wfmin=lf[u]; } }
    }
  }
  __shared__ float rv[256]; __shared__ unsigned rf[256];
  for (int r=0;r<16;++r){
    float bv = lv[0]; unsigned bf = lf[0];
    #pragma unroll
    for (int u=1;u<16;++u){ if (better(lv[u],lf[u],bv,bf)){ bv=lv[u]; bf=lf[u]; } }
    rv[tid]=bv; rf[tid]=bf; __syncthreads();
    for (int s=128;s;s>>=1){
      if (tid<s && better(rv[tid+s],rf[tid+s],rv[tid],rf[tid])){ rv[tid]=rv[tid+s]; rf[tid]=rf[tid+s]; }
      __syncthreads();
    }
    if (tid==0){ p.pkv[blockIdx.x*16+r]=rv[0]; p.pkf[blockIdx.x*16+r]=rf[0]; }
    float wv = rv[0]; unsigned wf = rf[0];
    __syncthreads();
    #pragma unroll
    for (int u=0;u<16;++u){ if (lf[u]==wf && lv[u]==wv){ lv[u]=-3e38f; lf[u]=0xFFFFFFFFu; } }
    __syncthreads();
  }
}

// ---------------- K4a: global merge + beam-state update (1 block) ----------
__global__ __launch_bounds__(512) void k4a_merge(P p, int t){
  int tid = threadIdx.x;
  __shared__ float mv[512]; __shared__ unsigned mu[512];
  __shared__ float rv[512]; __shared__ unsigned rf[512];
  __shared__ int wq[16], wc[16]; __shared__ float wvv[16], wloc[16];
  mv[tid] = p.pkv[tid]; mu[tid] = p.pkf[tid];
  __syncthreads();
  for (int r=0;r<16;++r){
    rv[tid]=mv[tid]; rf[tid]=mu[tid]; __syncthreads();
    for (int s=256;s;s>>=1){
      if (tid<s && better(rv[tid+s],rf[tid+s],rv[tid],rf[tid])){ rv[tid]=rv[tid+s]; rf[tid]=rf[tid+s]; }
      __syncthreads();
    }
    if (tid==0){
      unsigned bf = rf[0];
      int q = (int)(bf / VTT); int c = (int)(bf - (unsigned)q*VTT);
      wq[r]=q; wc[r]=c; wvv[r]=rv[0];
    }
    if (mu[tid]==rf[0] && mv[tid]==rv[0]){ mv[tid]=-3e38f; mu[tid]=0xFFFFFFFFu; }
    __syncthreads();
  }
  if (tid < 16){
    int r = tid, q = wq[r], c = wc[r];
    float local = (c < VP1) ? (p.logits[(size_t)q*VP1 + c] - p.lse[q] + p.dlp[q*RP1])
                            : p.dlp[q*RP1 + (c - NV)];
    wloc[r] = local;
    int it;
    if (c > NV){
      int ridx = c - VP1;
      it = (int)p.ppls[((size_t)r*NR + ridx)*6 + 4] + NV;
    } else it = c;
    p.qsel[r] = q; p.itsel[r] = it;
    p.lpsum[r] = (c==0) ? -1000.0f : wvv[r];
  }
  __syncthreads();
  const int*   bss = (t&1)? p.bs1 : p.bs0;   int*   bsd = (t&1)? p.bs0 : p.bs1;
  const float* lps = (t&1)? p.blp1: p.blp0;  float* lpd = (t&1)? p.blp0: p.blp1;
  for (int o=tid; o<(t+1)*16; o+=512){
    int row = o>>4, b = o&15, q = wq[b];
    if (row < t){ bsd[row*NB+b] = bss[row*NB+q]; lpd[row*NB+b] = lps[row*NB+q]; }
    else        { bsd[t*NB+b]   = wc[b];         lpd[t*NB+b]   = wloc[b]; }
  }
  const float* ms = (t==0) ? p.pnt : ((t&1)? p.mask1 : p.mask0);
  float* md = (t&1)? p.mask0 : p.mask1;
  for (int o=tid; o<16*128; o+=512){
    int b = o>>7, jj = o&127;
    if (jj < RP1){
      int q = wq[b], c = wc[b];
      float m = ms[q*RP1 + jj];
      if (jj == 0) m = 0.f;
      if (c > NV && jj == (c - VP1) + 1) m = 1.0f;
      md[b*RP1 + jj] = m;
    }
  }
}

// ---------------- K4b: gather + attention + ctx (16 blocks x 1024) ----------
__global__ __launch_bounds__(1024) void k4b_attn(P p, int t){
  int bi = blockIdx.x, tid = threadIdx.x;
  __shared__ float hhs[ND];
  __shared__ float att[128];
  __shared__ float msk[RP1];
  int q = p.qsel[bi], it = p.itsel[bi];
  const float* hprev = (t==0) ? p.h0 : p.hst;
  float hv = hprev[(size_t)q*ND + tid];
  hhs[tid] = hv;
  p.hhgT[tid*NB + bi] = hv;
  p.xtT[tid*NB + bi] = p.embed[(size_t)it*ND + tid];
  const float* md = (t&1)? p.mask0 : p.mask1;
  if (tid < RP1) msk[tid] = md[bi*RP1 + tid];
  if (tid >= 100 && tid < 128) att[tid] = -INFINITY;
  __syncthreads();
  int w = tid >> 6, l = tid & 63;
  for (int r=w; r<NR; r+=16){
    const float* pf = p.pool + ((size_t)bi*NR + r)*ND;
    float s = 0.f;
    #pragma unroll
    for (int c=0;c<4;++c){
      float4 pv = *reinterpret_cast<const float4*>(pf + c*256 + l*4);
      float4 hvv = *reinterpret_cast<const float4*>(&hhs[c*256 + l*4]);
      s = fmaf(pv.x,hvv.x,s); s = fmaf(pv.y,hvv.y,s);
      s = fmaf(pv.z,hvv.z,s); s = fmaf(pv.w,hvv.w,s);
    }
    #pragma unroll
    for (int off=32; off; off>>=1) s += __shfl_down(s, off);
    if (l == 0) att[r] = (msk[r+1] > 0.f) ? NEGF : s*0.03125f;
  }
  __syncthreads();
  if (tid < 64){
    float a = att[tid], a2 = att[tid+64];
    float m = fmaxf(a, a2);
    #pragma unroll
    for (int off=32; off; off>>=1) m = fmaxf(m, __shfl_down(m, off));
    m = __shfl(m, 0);
    float e1 = expf(a - m);
    float e2 = (tid+64 < 128) ? expf(a2 - m) : 0.f;
    float s = e1 + e2;
    #pragma unroll
    for (int off=32; off; off>>=1) s += __shfl_down(s, off);
    s = __shfl(s, 0);
    att[tid] = e1 / s;
    att[tid+64] = e2 / s;
  }
  __syncthreads();
  float cx = 0.f;
  const float* pb = p.pool + (size_t)bi*NR*ND + tid;
  #pragma unroll 4
  for (int r=0;r<NR;++r) cx = fmaf(att[r], pb[(size_t)r*ND], cx);
  p.ctxT[tid*NB + bi] = cx;
}

// ---------------- K5: fused 3-matrix RNN GEMM partials (128 blocks) ----------
__global__ __launch_bounds__(256) void k5_rnn(const float* __restrict__ Wx,
    const float* __restrict__ Wh, const float* __restrict__ Wc,
    const float* __restrict__ xtT, const float* __restrict__ hhgT,
    const float* __restrict__ ctxT, float* __restrict__ part){
  int tid = threadIdx.x;
  int jb = blockIdx.x & 3, ks = blockIdx.x >> 2;
  int j = jb*256 + tid;
  int k0 = ks*32;
  float acc[16];
  #pragma unroll
  for (int b=0;b<16;++b) acc[b]=0.f;
  for (int k=k0;k<k0+32;++k){
    float wx = Wx[(size_t)k*ND + j];
    float wh = Wh[(size_t)k*ND + j];
    float wc = Wc[(size_t)k*ND + j];
    const float4* xv = reinterpret_cast<const float4*>(xtT)  + (size_t)k*4;
    const float4* hv = reinterpret_cast<const float4*>(hhgT) + (size_t)k*4;
    const float4* cv = reinterpret_cast<const float4*>(ctxT) + (size_t)k*4;
    float4 x0=xv[0],x1=xv[1],x2=xv[2],x3=xv[3];
    float4 h0=hv[0],h1=hv[1],h2=hv[2],h3=hv[3];
    float4 c0=cv[0],c1=cv[1],c2=cv[2],c3=cv[3];
    acc[0]=fmaf(x0.x,wx,fmaf(h0.x,wh,fmaf(c0.x,wc,acc[0])));
    acc[1]=fmaf(x0.y,wx,fmaf(h0.y,wh,fmaf(c0.y,wc,acc[1])));
    acc[2]=fmaf(x0.z,wx,fmaf(h0.z,wh,fmaf(c0.z,wc,acc[2])));
    acc[3]=fmaf(x0.w,wx,fmaf(h0.w,wh,fmaf(c0.w,wc,acc[3])));
    acc[4]=fmaf(x1.x,wx,fmaf(h1.x,wh,fmaf(c1.x,wc,acc[4])));
    acc[5]=fmaf(x1.y,wx,fmaf(h1.y,wh,fmaf(c1.y,wc,acc[5])));
    acc[6]=fmaf(x1.z,wx,fmaf(h1.z,wh,fmaf(c1.z,wc,acc[6])));
    acc[7]=fmaf(x1.w,wx,fmaf(h1.w,wh,fmaf(c1.w,wc,acc[7])));
    acc[8]=fmaf(x2.x,wx,fmaf(h2.x,wh,fmaf(c2.x,wc,acc[8])));
    acc[9]=fmaf(x2.y,wx,fmaf(h2.y,wh,fmaf(c2.y,wc,acc[9])));
    acc[10]=fmaf(x2.z,wx,fmaf(h2.z,wh,fmaf(c2.z,wc,acc[10])));
    acc[11]=fmaf(x2.w,wx,fmaf(h2.w,wh,fmaf(c2.w,wc,acc[11])));
    acc[12]=fmaf(x3.x,wx,fmaf(h3.x,wh,fmaf(c3.x,wc,acc[12])));
    acc[13]=fmaf(x3.y,wx,fmaf(h3.y,wh,fmaf(c3.y,wc,acc[13])));
    acc[14]=fmaf(x3.z,wx,fmaf(h3.z,wh,fmaf(c3.z,wc,acc[14])));
    acc[15]=fmaf(x3.w,wx,fmaf(h3.w,wh,fmaf(c3.w,wc,acc[15])));
  }
  #pragma unroll
  for (int b=0;b<16;++b) part[((size_t)ks*16 + b)*ND + j] = acc[b];
}

// ---------------- K6: reduce partials + tanh -> h_new ----------------
__global__ __launch_bounds__(256) void k6_tanh(P p){
  int o = blockIdx.x*256 + threadIdx.x;
  int b = o >> 10, j = o & 1023;
  float s = 0.f;
  for (int ks=0; ks<32; ++ks) s += p.part[((size_t)ks*16 + b)*ND + j];
  float hv = tanhf(s);
  p.hst[o] = hv;
  p.rnnT[j*NB + b] = hv;
}

// ---------------- K7: pack outputs (f32) ----------------
__global__ __launch_bounds__(256) void k7_out(P p, float* out){
  int i = blockIdx.x*256 + threadIdx.x;
  if (i < NT*NB)            out[i] = (float)p.bs0[i];
  else if (i < 2*NT*NB)     out[i] = p.blp0[i - NT*NB];
  else if (i < 2*NT*NB+NB)  out[i] = p.lpsum[i - 2*NT*NB];
}

// ---------------- host ----------------
extern "C" void kernel_launch(void* const* d_in, const int* in_sizes, int n_in,
                              void* d_out, int out_size, void* d_ws, size_t ws_size,
                              hipStream_t stream) {
  P p;
  p.embed = (const float*)d_in[0];
  p.Wx    = (const float*)d_in[1];
  p.Wh    = (const float*)d_in[2];
  p.Wc    = (const float*)d_in[3];
  p.Wl    = (const float*)d_in[4];
  p.Wd    = (const float*)d_in[5];
  p.rnn0  = (const float*)d_in[6];
  p.det0  = (const float*)d_in[7];
  p.h0    = (const float*)d_in[8];
  p.pool  = (const float*)d_in[9];
  p.ppls  = (const float*)d_in[10];
  p.pnt   = (const float*)d_in[11];

  char* ws = (char*)d_ws;
  size_t off = 0;
  auto A = [&](size_t nfloats)->void* {
    void* r = ws + off;
    off += ((nfloats*4) + 255) & ~(size_t)255;
    return r;
  };
  p.logits = (float*)A((size_t)NB*VP1);
  p.lse    = (float*)A(NB);
  p.dlp    = (float*)A(NB*RP1);
  p.rnnT   = (float*)A(ND*NB);
  p.hst    = (float*)A(NB*ND);
  p.hhgT   = (float*)A(ND*NB);
  p.xtT    = (float*)A(ND*NB);
  p.ctxT   = (float*)A(ND*NB);
  p.mask0  = (float*)A(NB*RP1);
  p.mask1  = (float*)A(NB*RP1);
  p.bs0    = (int*)A(NT*NB);
  p.bs1    = (int*)A(NT*NB);
  p.blp0   = (float*)A(NT*NB);
  p.blp1   = (float*)A(NT*NB);
  p.lpsum  = (float*)A(NB);
  p.pkv    = (float*)A(512);
  p.pkf    = (unsigned*)A(512);
  p.part   = (float*)A((size_t)32*NB*ND);
  p.blkM   = (float*)A(NB*LSE_TILES);
  p.blkS   = (float*)A(NB*LSE_TILES);
  p.qsel   = (int*)A(16);
  p.itsel  = (int*)A(16);
  if (off > ws_size) return;

  k0_init<<<64,256,0,stream>>>(p);
  for (int t=0; t<NT; ++t){
    k1_logits<<<391,256,0,stream>>>(p.Wl, p.rnnT, p.logits);
    k2a_lsepart<<<dim3(LSE_TILES,NB),256,0,stream>>>(p.logits, p.blkM, p.blkS);
    k2b_lse_det<<<32,512,0,stream>>>(p, t);
    k3_cand<<<32,256,0,stream>>>(p, t);
    k4a_merge<<<1,512,0,stream>>>(p, t);
    k4b_attn<<<NB,1024,0,stream>>>(p, t);
    k5_rnn<<<128,256,0,stream>>>(p.Wx, p.Wh, p.Wc, p.xtT, p.hhgT, p.ctxT, p.part);
    k6_tanh<<<64,256,0,stream>>>(p);
  }
  k7_out<<<3,256,0,stream>>>(p, (float*)d_out);
}

// Round 4
// 3762.653 us; speedup vs baseline: 3.1142x; 1.7053x over previous
//
#include <hip/hip_runtime.h>
#include <math.h>

#define NB 16
#define NR 100
#define NV 50000
#define ND 1024
#define NT 20
#define VP1 50001
#define VP1R 50004     // padded row stride (float4-aligned rows)
#define VTT 50101
#define RP1 101
#define NEGF (-1e10f)
#define LSE_TILES 49   // ceil(50001/1024)
#define NSLICE 13      // 13*4096 = 53248 >= 50101
#define NBLK3 (NB*NSLICE)      // 208
#define MERGE_N (NBLK3*16)     // 3328

struct P {
  const float* embed; const float* Wx; const float* Wh; const float* Wc;
  const float* Wl; const float* Wd; const float* rnn0; const float* det0;
  const float* h0; const float* pool; const float* ppls; const float* pnt;
  float* logits;   // [16][VP1R]
  float* lse;      // [16]
  float* dlp;      // [16][101]
  float* rnnT;     // [1024][16]
  float* hst;      // [16][1024]
  float* hhgT;     // [1024][16]
  float* xtT;      // [1024][16]
  float* ctxT;     // [1024][16]
  float* mask0; float* mask1;       // [16][101] ping-pong
  int* bs0; int* bs1;               // [20][16] ping-pong
  float* blp0; float* blp1;         // [20][16] ping-pong
  float* lpsum;    // [16]
  float* pkv; unsigned* pkf;        // [MERGE_N]
  float* part;     // [32][16][1024]
  float* blkM; float* blkS;         // [16*49]
  int* qsel; int* itsel;            // [16]
};

__device__ __forceinline__ bool better(float av, unsigned af, float bv, unsigned bf){
  return (av > bv) || (av == bv && af < bf);
}
__device__ __forceinline__ void lsecomb(float& m, float& s, float m2, float s2){
  float M = fmaxf(m, m2);
  if (M == -INFINITY){ m = M; s = 0.f; return; }
  s = s*expf(m - M) + s2*expf(m2 - M);
  m = M;
}

// ---------------- K0: init ----------------
__global__ __launch_bounds__(256) void k0_init(P p){
  int i = blockIdx.x*256 + threadIdx.x;
  int n = gridDim.x*256;
  for (int o=i; o<NB*ND; o+=n){ int b=o>>10, k=o&1023; p.rnnT[k*NB+b] = p.rnn0[o]; }
  for (int o=i; o<NT*NB; o+=n){ p.bs0[o]=0; p.bs1[o]=0; p.blp0[o]=0.f; p.blp1[o]=0.f; }
  for (int o=i; o<NB; o+=n) p.lpsum[o]=0.f;
}

// ---------------- K1: logits = rnn_out @ Wl ----------------
__global__ __launch_bounds__(256) void k1_logits(const float* __restrict__ Wl,
    const float* __restrict__ rnnT, float* __restrict__ logits){
  __shared__ float red[4][128][17];
  int tid = threadIdx.x;
  int jt = tid & 63, ks = tid >> 6;
  int B0 = blockIdx.x * 128;
  int j0 = B0 + jt, j1 = j0 + 64;
  const float* p0 = Wl + (j0 < VP1 ? j0 : VP1-1);
  const float* p1 = Wl + (j1 < VP1 ? j1 : VP1-1);
  float a0[16], a1[16];
  #pragma unroll
  for (int b=0;b<16;++b){ a0[b]=0.f; a1[b]=0.f; }
  const float4* rT = reinterpret_cast<const float4*>(rnnT);
  size_t koff = (size_t)(ks*256) * VP1;
  for (int k=ks*256; k<ks*256+256; ++k, koff += VP1){
    float w0 = p0[koff], w1 = p1[koff];
    float4 r0 = rT[k*4+0], r1 = rT[k*4+1], r2 = rT[k*4+2], r3 = rT[k*4+3];
    a0[0]=fmaf(r0.x,w0,a0[0]);  a1[0]=fmaf(r0.x,w1,a1[0]);
    a0[1]=fmaf(r0.y,w0,a0[1]);  a1[1]=fmaf(r0.y,w1,a1[1]);
    a0[2]=fmaf(r0.z,w0,a0[2]);  a1[2]=fmaf(r0.z,w1,a1[2]);
    a0[3]=fmaf(r0.w,w0,a0[3]);  a1[3]=fmaf(r0.w,w1,a1[3]);
    a0[4]=fmaf(r1.x,w0,a0[4]);  a1[4]=fmaf(r1.x,w1,a1[4]);
    a0[5]=fmaf(r1.y,w0,a0[5]);  a1[5]=fmaf(r1.y,w1,a1[5]);
    a0[6]=fmaf(r1.z,w0,a0[6]);  a1[6]=fmaf(r1.z,w1,a1[6]);
    a0[7]=fmaf(r1.w,w0,a0[7]);  a1[7]=fmaf(r1.w,w1,a1[7]);
    a0[8]=fmaf(r2.x,w0,a0[8]);  a1[8]=fmaf(r2.x,w1,a1[8]);
    a0[9]=fmaf(r2.y,w0,a0[9]);  a1[9]=fmaf(r2.y,w1,a1[9]);
    a0[10]=fmaf(r2.z,w0,a0[10]); a1[10]=fmaf(r2.z,w1,a1[10]);
    a0[11]=fmaf(r2.w,w0,a0[11]); a1[11]=fmaf(r2.w,w1,a1[11]);
    a0[12]=fmaf(r3.x,w0,a0[12]); a1[12]=fmaf(r3.x,w1,a1[12]);
    a0[13]=fmaf(r3.y,w0,a0[13]); a1[13]=fmaf(r3.y,w1,a1[13]);
    a0[14]=fmaf(r3.z,w0,a0[14]); a1[14]=fmaf(r3.z,w1,a1[14]);
    a0[15]=fmaf(r3.w,w0,a0[15]); a1[15]=fmaf(r3.w,w1,a1[15]);
  }
  #pragma unroll
  for (int b=0;b<16;++b){ red[ks][jt][b] = a0[b]; red[ks][jt+64][b] = a1[b]; }
  __syncthreads();
  int jl = tid & 127, bh = tid >> 7;
  int j = B0 + jl;
  #pragma unroll
  for (int i=0;i<8;++i){
    int b = i*2 + bh;
    float v = red[0][jl][b] + red[1][jl][b] + red[2][jl][b] + red[3][jl][b];
    if (j < VP1) logits[(size_t)b*VP1R + j] = v;
  }
}

// ---------------- K2a: per-tile LSE partials (49 x 16 blocks) ----------------
__global__ __launch_bounds__(256) void k2a_lsepart(const float* __restrict__ logits,
    float* __restrict__ blkM, float* __restrict__ blkS){
  int tile = blockIdx.x, b = blockIdx.y;
  int tid = threadIdx.x;
  const float* lr = logits + (size_t)b*VP1R + tile*1024;
  int lim = VP1 - tile*1024;
  float m = -INFINITY, s = 0.f;
  #pragma unroll
  for (int c=0;c<4;++c){
    int j = c*256 + tid;
    if (j < lim){
      float x = lr[j];
      if (x > m){ s = s*expf(m-x) + 1.f; m = x; }
      else s += expf(x-m);
    }
  }
  #pragma unroll
  for (int off=32; off; off>>=1){
    float m2 = __shfl_down(m, off), s2 = __shfl_down(s, off);
    lsecomb(m, s, m2, s2);
  }
  __shared__ float wm[4], ws[4];
  int w = tid >> 6;
  if ((tid & 63) == 0){ wm[w] = m; ws[w] = s; }
  __syncthreads();
  if (tid == 0){
    float M = wm[0], S = ws[0];
    lsecomb(M, S, wm[1], ws[1]);
    lsecomb(M, S, wm[2], ws[2]);
    lsecomb(M, S, wm[3], ws[3]);
    blkM[b*LSE_TILES + tile] = M; blkS[b*LSE_TILES + tile] = S;
  }
}

// ---------------- K2b: lse combine (blocks 0-15) + det head (blocks 16-31) ---
__global__ __launch_bounds__(512) void k2b_lse_det(P p, int t){
  int bx = blockIdx.x, tid = threadIdx.x;
  if (bx < 16){
    if (tid < 64){
      int b = bx;
      float m = -INFINITY, s = 0.f;
      if (tid < LSE_TILES){ m = p.blkM[b*LSE_TILES + tid]; s = p.blkS[b*LSE_TILES + tid]; }
      #pragma unroll
      for (int off=32; off; off>>=1){
        float m2 = __shfl_down(m, off), s2 = __shfl_down(s, off);
        lsecomb(m, s, m2, s2);
      }
      if (tid == 0) p.lse[b] = m + logf(s);
    }
    return;
  }
  int b = bx - 16;
  __shared__ float dred[4][129];
  __shared__ float ddet[128];
  int jj = tid & 127, ks = tid >> 7;
  if (t == 0){
    if (tid < 128) ddet[tid] = (tid < RP1) ? p.det0[b*RP1 + tid] : -INFINITY;
    __syncthreads();
  } else {
    float a = 0.f;
    if (jj < RP1){
      const float* hr = p.hst + b*ND;
      for (int k=ks*256; k<ks*256+256; ++k)
        a = fmaf(hr[k], p.Wd[(size_t)k*RP1 + jj], a);
    }
    dred[ks][jj] = a;
    __syncthreads();
    if (tid < 128)
      ddet[tid] = (tid < RP1) ? (dred[0][tid]+dred[1][tid]+dred[2][tid]+dred[3][tid]) : -INFINITY;
    __syncthreads();
  }
  if (tid < 64){
    float a = ddet[tid], a2 = ddet[tid+64];
    float m = fmaxf(a, a2);
    #pragma unroll
    for (int off=32; off; off>>=1) m = fmaxf(m, __shfl_down(m, off));
    m = __shfl(m, 0);
    float e1 = (tid < RP1) ? expf(a - m) : 0.f;
    float e2 = (tid+64 < RP1) ? expf(a2 - m) : 0.f;
    float s = e1 + e2;
    #pragma unroll
    for (int off=32; off; off>>=1) s += __shfl_down(s, off);
    s = __shfl(s, 0);
    float ls = logf(s);
    if (tid < RP1)     p.dlp[b*RP1 + tid]      = a  - m - ls;
    if (tid+64 < RP1)  p.dlp[b*RP1 + tid + 64] = a2 - m - ls;
  }
}

// ------- K3: candidates + per-block top16 (13 slices x 16 beams = 208 blocks) -
__global__ __launch_bounds__(256) void k3_cand(P p, int t){
  int tid = threadIdx.x;
  int slice = blockIdx.x, b = blockIdx.y;
  float lv[16]; unsigned lf[16];
  float cA = p.lpsum[b] - p.lse[b] + p.dlp[b*RP1];
  float cB = p.lpsum[b];
  bool dead = (t==0 && b>0);
  const float* lrow = p.logits + (size_t)b*VP1R;
  const float* drow = p.dlp + b*RP1;
  unsigned fbase = (unsigned)(b*VTT);
  int j0 = slice*4096 + (tid<<2);
  #pragma unroll
  for (int c=0;c<4;++c){
    int j = j0 + c*1024;
    bool vec = (j+4 <= VP1);
    float4 lg = make_float4(0.f,0.f,0.f,0.f);
    if (vec) lg = *reinterpret_cast<const float4*>(lrow + j);
    float le[4] = {lg.x, lg.y, lg.z, lg.w};
    #pragma unroll
    for (int e=0;e<4;++e){
      int jj = j + e;
      float v; unsigned f;
      if (jj < VP1){ v = cA + (vec ? le[e] : lrow[jj]); f = fbase + (unsigned)jj; }
      else if (jj < VTT){ v = cB + drow[jj - NV]; f = fbase + (unsigned)jj; }
      else { v = -3e38f; f = 0xFFFFFFFFu; }
      if (dead && f != 0xFFFFFFFFu) v = NEGF;
      lv[c*4+e] = v; lf[c*4+e] = f;
    }
  }
  __shared__ float wmv[4]; __shared__ unsigned wmf[4];
  __shared__ float sbv; __shared__ unsigned sbf;
  int lane = tid & 63, wid = tid >> 6;
  int blin = b*NSLICE + slice;
  for (int r=0;r<16;++r){
    float bv = lv[0]; unsigned bf = lf[0];
    #pragma unroll
    for (int u=1;u<16;++u) if (better(lv[u],lf[u],bv,bf)){ bv=lv[u]; bf=lf[u]; }
    #pragma unroll
    for (int off=32; off; off>>=1){
      float ov = __shfl_down(bv, off); unsigned of = __shfl_down(bf, off);
      if (better(ov,of,bv,bf)){ bv=ov; bf=of; }
    }
    if (lane==0){ wmv[wid]=bv; wmf[wid]=bf; }
    __syncthreads();
    if (tid==0){
      float mv2=wmv[0]; unsigned mf2=wmf[0];
      #pragma unroll
      for (int w=1;w<4;++w) if (better(wmv[w],wmf[w],mv2,mf2)){ mv2=wmv[w]; mf2=wmf[w]; }
      p.pkv[blin*16+r]=mv2; p.pkf[blin*16+r]=mf2;
      sbv=mv2; sbf=mf2;
    }
    __syncthreads();
    unsigned WF = sbf;
    #pragma unroll
    for (int u=0;u<16;++u) if (lf[u]==WF){ lv[u]=-3e38f; lf[u]=0xFFFFFFFFu; }
  }
}

// ---------------- K4a: global merge (3328 entries) + beam-state update -------
__global__ __launch_bounds__(1024) void k4a_merge(P p, int t){
  int tid = threadIdx.x;
  float ev[4]; unsigned ef[4];
  #pragma unroll
  for (int c=0;c<4;++c){
    int idx = c*1024 + tid;
    if (idx < MERGE_N){ ev[c]=p.pkv[idx]; ef[c]=p.pkf[idx]; }
    else { ev[c]=-3e38f; ef[c]=0xFFFFFFFFu; }
  }
  __shared__ float wmv[16]; __shared__ unsigned wmf[16];
  __shared__ float sbv; __shared__ unsigned sbf;
  __shared__ int wq[16], wc[16]; __shared__ float wvv[16], wloc[16];
  int lane = tid & 63, wid = tid >> 6;
  for (int r=0;r<16;++r){
    float bv = ev[0]; unsigned bf = ef[0];
    #pragma unroll
    for (int c=1;c<4;++c) if (better(ev[c],ef[c],bv,bf)){ bv=ev[c]; bf=ef[c]; }
    #pragma unroll
    for (int off=32; off; off>>=1){
      float ov = __shfl_down(bv, off); unsigned of = __shfl_down(bf, off);
      if (better(ov,of,bv,bf)){ bv=ov; bf=of; }
    }
    if (lane==0){ wmv[wid]=bv; wmf[wid]=bf; }
    __syncthreads();
    if (tid==0){
      float mv2=wmv[0]; unsigned mf2=wmf[0];
      #pragma unroll
      for (int w=1;w<16;++w) if (better(wmv[w],wmf[w],mv2,mf2)){ mv2=wmv[w]; mf2=wmf[w]; }
      unsigned q = mf2 / VTT; unsigned c = mf2 - q*VTT;
      wq[r]=(int)q; wc[r]=(int)c; wvv[r]=mv2;
      sbv=mv2; sbf=mf2;
    }
    __syncthreads();
    unsigned WF = sbf;
    #pragma unroll
    for (int c=0;c<4;++c) if (ef[c]==WF){ ev[c]=-3e38f; ef[c]=0xFFFFFFFFu; }
  }
  if (tid < 16){
    int r = tid, q = wq[r], c = wc[r];
    float local = (c < VP1) ? (p.logits[(size_t)q*VP1R + c] - p.lse[q] + p.dlp[q*RP1])
                            : p.dlp[q*RP1 + (c - NV)];
    wloc[r] = local;
    int it;
    if (c > NV){
      int ridx = c - VP1;
      it = (int)p.ppls[((size_t)r*NR + ridx)*6 + 4] + NV;
    } else it = c;
    p.qsel[r] = q; p.itsel[r] = it;
    p.lpsum[r] = (c==0) ? -1000.0f : wvv[r];
  }
  __syncthreads();
  const int*   bss = (t&1)? p.bs1 : p.bs0;   int*   bsd = (t&1)? p.bs0 : p.bs1;
  const float* lps = (t&1)? p.blp1: p.blp0;  float* lpd = (t&1)? p.blp0: p.blp1;
  for (int o=tid; o<(t+1)*16; o+=1024){
    int row = o>>4, b = o&15, q = wq[b];
    if (row < t){ bsd[row*NB+b] = bss[row*NB+q]; lpd[row*NB+b] = lps[row*NB+q]; }
    else        { bsd[t*NB+b]   = wc[b];         lpd[t*NB+b]   = wloc[b]; }
  }
  const float* ms = (t==0) ? p.pnt : ((t&1)? p.mask1 : p.mask0);
  float* md = (t&1)? p.mask0 : p.mask1;
  for (int o=tid; o<16*128; o+=1024){
    int b = o>>7, jj = o&127;
    if (jj < RP1){
      int q = wq[b], c = wc[b];
      float m = ms[q*RP1 + jj];
      if (jj == 0) m = 0.f;
      if (c > NV && jj == (c - VP1) + 1) m = 1.0f;
      md[b*RP1 + jj] = m;
    }
  }
}

// ---------------- K4b: gather + attention + ctx (16 blocks x 1024) ----------
__global__ __launch_bounds__(1024) void k4b_attn(P p, int t){
  int bi = blockIdx.x, tid = threadIdx.x;
  __shared__ float hhs[ND];
  __shared__ float att[128];
  __shared__ float msk[RP1];
  int q = p.qsel[bi], it = p.itsel[bi];
  const float* hprev = (t==0) ? p.h0 : p.hst;
  float hv = hprev[(size_t)q*ND + tid];
  hhs[tid] = hv;
  p.hhgT[tid*NB + bi] = hv;
  p.xtT[tid*NB + bi] = p.embed[(size_t)it*ND + tid];
  const float* md = (t&1)? p.mask0 : p.mask1;
  if (tid < RP1) msk[tid] = md[bi*RP1 + tid];
  if (tid >= 100 && tid < 128) att[tid] = -INFINITY;
  __syncthreads();
  int w = tid >> 6, l = tid & 63;
  for (int r=w; r<NR; r+=16){
    const float* pf = p.pool + ((size_t)bi*NR + r)*ND;
    float s = 0.f;
    #pragma unroll
    for (int c=0;c<4;++c){
      float4 pv = *reinterpret_cast<const float4*>(pf + c*256 + l*4);
      float4 hvv = *reinterpret_cast<const float4*>(&hhs[c*256 + l*4]);
      s = fmaf(pv.x,hvv.x,s); s = fmaf(pv.y,hvv.y,s);
      s = fmaf(pv.z,hvv.z,s); s = fmaf(pv.w,hvv.w,s);
    }
    #pragma unroll
    for (int off=32; off; off>>=1) s += __shfl_down(s, off);
    if (l == 0) att[r] = (msk[r+1] > 0.f) ? NEGF : s*0.03125f;
  }
  __syncthreads();
  if (tid < 64){
    float a = att[tid], a2 = att[tid+64];
    float m = fmaxf(a, a2);
    #pragma unroll
    for (int off=32; off; off>>=1) m = fmaxf(m, __shfl_down(m, off));
    m = __shfl(m, 0);
    float e1 = expf(a - m);
    float e2 = (tid+64 < 128) ? expf(a2 - m) : 0.f;
    float s = e1 + e2;
    #pragma unroll
    for (int off=32; off; off>>=1) s += __shfl_down(s, off);
    s = __shfl(s, 0);
    att[tid] = e1 / s;
    att[tid+64] = e2 / s;
  }
  __syncthreads();
  float cx = 0.f;
  const float* pb = p.pool + (size_t)bi*NR*ND + tid;
  #pragma unroll 4
  for (int r=0;r<NR;++r) cx = fmaf(att[r], pb[(size_t)r*ND], cx);
  p.ctxT[tid*NB + bi] = cx;
}

// ---------------- K5: fused 3-matrix RNN GEMM partials (128 blocks) ----------
__global__ __launch_bounds__(256) void k5_rnn(const float* __restrict__ Wx,
    const float* __restrict__ Wh, const float* __restrict__ Wc,
    const float* __restrict__ xtT, const float* __restrict__ hhgT,
    const float* __restrict__ ctxT, float* __restrict__ part){
  int tid = threadIdx.x;
  int jb = blockIdx.x & 3, ks = blockIdx.x >> 2;
  int j = jb*256 + tid;
  int k0 = ks*32;
  float acc[16];
  #pragma unroll
  for (int b=0;b<16;++b) acc[b]=0.f;
  for (int k=k0;k<k0+32;++k){
    float wx = Wx[(size_t)k*ND + j];
    float wh = Wh[(size_t)k*ND + j];
    float wc = Wc[(size_t)k*ND + j];
    const float4* xv = reinterpret_cast<const float4*>(xtT)  + (size_t)k*4;
    const float4* hv = reinterpret_cast<const float4*>(hhgT) + (size_t)k*4;
    const float4* cv = reinterpret_cast<const float4*>(ctxT) + (size_t)k*4;
    float4 x0=xv[0],x1=xv[1],x2=xv[2],x3=xv[3];
    float4 h0=hv[0],h1=hv[1],h2=hv[2],h3=hv[3];
    float4 c0=cv[0],c1=cv[1],c2=cv[2],c3=cv[3];
    acc[0]=fmaf(x0.x,wx,fmaf(h0.x,wh,fmaf(c0.x,wc,acc[0])));
    acc[1]=fmaf(x0.y,wx,fmaf(h0.y,wh,fmaf(c0.y,wc,acc[1])));
    acc[2]=fmaf(x0.z,wx,fmaf(h0.z,wh,fmaf(c0.z,wc,acc[2])));
    acc[3]=fmaf(x0.w,wx,fmaf(h0.w,wh,fmaf(c0.w,wc,acc[3])));
    acc[4]=fmaf(x1.x,wx,fmaf(h1.x,wh,fmaf(c1.x,wc,acc[4])));
    acc[5]=fmaf(x1.y,wx,fmaf(h1.y,wh,fmaf(c1.y,wc,acc[5])));
    acc[6]=fmaf(x1.z,wx,fmaf(h1.z,wh,fmaf(c1.z,wc,acc[6])));
    acc[7]=fmaf(x1.w,wx,fmaf(h1.w,wh,fmaf(c1.w,wc,acc[7])));
    acc[8]=fmaf(x2.x,wx,fmaf(h2.x,wh,fmaf(c2.x,wc,acc[8])));
    acc[9]=fmaf(x2.y,wx,fmaf(h2.y,wh,fmaf(c2.y,wc,acc[9])));
    acc[10]=fmaf(x2.z,wx,fmaf(h2.z,wh,fmaf(c2.z,wc,acc[10])));
    acc[11]=fmaf(x2.w,wx,fmaf(h2.w,wh,fmaf(c2.w,wc,acc[11])));
    acc[12]=fmaf(x3.x,wx,fmaf(h3.x,wh,fmaf(c3.x,wc,acc[12])));
    acc[13]=fmaf(x3.y,wx,fmaf(h3.y,wh,fmaf(c3.y,wc,acc[13])));
    acc[14]=fmaf(x3.z,wx,fmaf(h3.z,wh,fmaf(c3.z,wc,acc[14])));
    acc[15]=fmaf(x3.w,wx,fmaf(h3.w,wh,fmaf(c3.w,wc,acc[15])));
  }
  #pragma unroll
  for (int b=0;b<16;++b) part[((size_t)ks*16 + b)*ND + j] = acc[b];
}

// ---------------- K6: reduce partials + tanh -> h_new ----------------
__global__ __launch_bounds__(256) void k6_tanh(P p){
  int o = blockIdx.x*256 + threadIdx.x;
  int b = o >> 10, j = o & 1023;
  float s = 0.f;
  for (int ks=0; ks<32; ++ks) s += p.part[((size_t)ks*16 + b)*ND + j];
  float hv = tanhf(s);
  p.hst[o] = hv;
  p.rnnT[j*NB + b] = hv;
}

// ---------------- K7: pack outputs (f32) ----------------
__global__ __launch_bounds__(256) void k7_out(P p, float* out){
  int i = blockIdx.x*256 + threadIdx.x;
  if (i < NT*NB)            out[i] = (float)p.bs0[i];
  else if (i < 2*NT*NB)     out[i] = p.blp0[i - NT*NB];
  else if (i < 2*NT*NB+NB)  out[i] = p.lpsum[i - 2*NT*NB];
}

// ---------------- host ----------------
extern "C" void kernel_launch(void* const* d_in, const int* in_sizes, int n_in,
                              void* d_out, int out_size, void* d_ws, size_t ws_size,
                              hipStream_t stream) {
  P p;
  p.embed = (const float*)d_in[0];
  p.Wx    = (const float*)d_in[1];
  p.Wh    = (const float*)d_in[2];
  p.Wc    = (const float*)d_in[3];
  p.Wl    = (const float*)d_in[4];
  p.Wd    = (const float*)d_in[5];
  p.rnn0  = (const float*)d_in[6];
  p.det0  = (const float*)d_in[7];
  p.h0    = (const float*)d_in[8];
  p.pool  = (const float*)d_in[9];
  p.ppls  = (const float*)d_in[10];
  p.pnt   = (const float*)d_in[11];

  char* ws = (char*)d_ws;
  size_t off = 0;
  auto A = [&](size_t nfloats)->void* {
    void* r = ws + off;
    off += ((nfloats*4) + 255) & ~(size_t)255;
    return r;
  };
  p.logits = (float*)A((size_t)NB*VP1R);
  p.lse    = (float*)A(NB);
  p.dlp    = (float*)A(NB*RP1);
  p.rnnT   = (float*)A(ND*NB);
  p.hst    = (float*)A(NB*ND);
  p.hhgT   = (float*)A(ND*NB);
  p.xtT    = (float*)A(ND*NB);
  p.ctxT   = (float*)A(ND*NB);
  p.mask0  = (float*)A(NB*RP1);
  p.mask1  = (float*)A(NB*RP1);
  p.bs0    = (int*)A(NT*NB);
  p.bs1    = (int*)A(NT*NB);
  p.blp0   = (float*)A(NT*NB);
  p.blp1   = (float*)A(NT*NB);
  p.lpsum  = (float*)A(NB);
  p.pkv    = (float*)A(MERGE_N);
  p.pkf    = (unsigned*)A(MERGE_N);
  p.part   = (float*)A((size_t)32*NB*ND);
  p.blkM   = (float*)A(NB*LSE_TILES);
  p.blkS   = (float*)A(NB*LSE_TILES);
  p.qsel   = (int*)A(16);
  p.itsel  = (int*)A(16);
  if (off > ws_size) return;

  k0_init<<<64,256,0,stream>>>(p);
  for (int t=0; t<NT; ++t){
    k1_logits<<<391,256,0,stream>>>(p.Wl, p.rnnT, p.logits);
    k2a_lsepart<<<dim3(LSE_TILES,NB),256,0,stream>>>(p.logits, p.blkM, p.blkS);
    k2b_lse_det<<<32,512,0,stream>>>(p, t);
    k3_cand<<<dim3(NSLICE,NB),256,0,stream>>>(p, t);
    k4a_merge<<<1,1024,0,stream>>>(p, t);
    k4b_attn<<<NB,1024,0,stream>>>(p, t);
    k5_rnn<<<128,256,0,stream>>>(p.Wx, p.Wh, p.Wc, p.xtT, p.hhgT, p.ctxT, p.part);
    k6_tanh<<<64,256,0,stream>>>(p);
  }
  k7_out<<<3,256,0,stream>>>(p, (float*)d_out);
}